// Round 2
// baseline (66.640 us; speedup 1.0000x reference)
//
#include <hip/hip_runtime.h>

// N=375, C=5, F=64, D=13. Segment starts {0,12,25,38,51}, each 13 long.
// One 64-thread block (= one wave) per picture. Greedy bipartite argmin is
// done wave-parallel: lane t<25 owns Dmat cell (r=t/5, c=t%5); flat index
// == lane id, so (val,idx) lexicographic shfl-min == jnp.argmin tiebreak.

__global__ __launch_bounds__(64) void token_kernel(
    const float* __restrict__ picture,
    const float* __restrict__ t0, const float* __restrict__ t1,
    const float* __restrict__ t2, const float* __restrict__ t3,
    const float* __restrict__ t4,
    float* __restrict__ out)
{
    const int n = blockIdx.x;   // picture index
    const int t = threadIdx.x;  // 0..63

    __shared__ float T[5][13];   // stacked tokens
    __shared__ float pic[5][64]; // picture[n]

    // ---- tokens -> LDS via if-chain (no runtime-indexed pointer array =
    //      no scratch spill). 65 elements; lane 0 picks up the 65th.
    if (t < 13)      T[0][t]      = t0[t];
    else if (t < 26) T[1][t - 13] = t1[t - 13];
    else if (t < 39) T[2][t - 26] = t2[t - 26];
    else if (t < 52) T[3][t - 39] = t3[t - 39];
    else             T[4][t - 52] = t4[t - 52];   // t=52..63 -> j=0..11
    if (t == 0)      T[4][12]     = t4[12];

    // ---- picture row n: 320 contiguous floats, coalesced, kept in regs too
    const float* p = picture + n * 320;
    float v[5];
#pragma unroll
    for (int c = 0; c < 5; ++c) {
        v[c] = p[c * 64 + t];
        pic[c][t] = v[c];
    }

    const int row = t / 5;   // meaningful for t<25
    const int col = t % 5;

    // ---- fullsq[c] via shuffle reduction; broadcast from lane 0 and keep
    //      only the one matching my row (no LDS round-trip, no extra sync).
    float myfullsq = 0.f;
#pragma unroll
    for (int c = 0; c < 5; ++c) {
        float s = v[c] * v[c];
#pragma unroll
        for (int off = 32; off > 0; off >>= 1)
            s += __shfl_down(s, off, 64);
        float tot = __shfl(s, 0, 64);
        if (row == c) myfullsq = tot;
    }

    __syncthreads();  // T and pic visible to all lanes

    // ---- Dmat cell for lane t<25, exact reference float order:
    //      (full_sq - seg_sq) + diff_sq, j accumulated 0..12 sequentially.
    const int starts[5] = {0, 12, 25, 38, 51};
    float dval = 1e30f;
    if (t < 25) {
        const int start = starts[col];
        float segsq = 0.f, diffsq = 0.f;
        for (int j = 0; j < 13; ++j) {
            float x = pic[row][start + j];
            float d = x - T[col][j];
            segsq  += x * x;
            diffsq += d * d;
        }
        dval = (myfullsq - segsq) + diffsq;
    }

    // ---- greedy assignment, wave-parallel: 5 rounds of 32-lane argmin.
    //      Lanes >=25 hold +INF. (val,idx) lexicographic min == first-flat-
    //      index tiebreak of jnp.argmin. All state in registers.
    bool alive = (t < 25);
    int my_assign = 0;   // lane r<5 ends holding assign[r]
#pragma unroll
    for (int it = 0; it < 5; ++it) {
        float mval = alive ? dval : 1e30f;
        int   midx = t;
#pragma unroll
        for (int off = 16; off > 0; off >>= 1) {
            float ov = __shfl_down(mval, off, 64);
            int   oi = __shfl_down(midx, off, 64);
            if (ov < mval || (ov == mval && oi < midx)) { mval = ov; midx = oi; }
        }
        const int widx = __shfl(midx, 0, 64);  // lane 0 has the winner
        const int br = widx / 5, bc = widx % 5;
        if (row == br || col == bc) alive = false;
        if (t == br) my_assign = bc;
    }

    // ---- output: out[n,r,f] = T[assign[r]][f-start_r] inside segment r, 0
    //      elsewhere. Writes all 320 elements (d_out is poisoned each call).
    float* o = out + n * 320;
#pragma unroll
    for (int r = 0; r < 5; ++r) {
        const int ar = __shfl(my_assign, r, 64);
        const int j = t - starts[r];
        const float val = (j >= 0 && j < 13) ? T[ar][j] : 0.f;
        o[r * 64 + t] = val;
    }
}

extern "C" void kernel_launch(void* const* d_in, const int* in_sizes, int n_in,
                              void* d_out, int out_size, void* d_ws, size_t ws_size,
                              hipStream_t stream) {
    const float* picture = (const float*)d_in[0];
    token_kernel<<<dim3(375), dim3(64), 0, stream>>>(
        picture,
        (const float*)d_in[1], (const float*)d_in[2], (const float*)d_in[3],
        (const float*)d_in[4], (const float*)d_in[5],
        (float*)d_out);
}